// Round 13
// baseline (563.707 us; speedup 1.0000x reference)
//
#include <hip/hip_runtime.h>
#include <hip/hip_bf16.h>

#define D 64
#define CAP 64    // fixed CSR row capacity; deg ~ Poisson(16), P(deg>=64) ~ 1e-20
#define NXCD 8    // MI355X: 8 XCDs
#define EPT 4     // edges per thread per fill chunk (one dwordx4 col load)
#define GRID 1024 // co-residency provable: LDS 25KB -> 6 blk/CU, launch_bounds -> >=4 blk/CU
#define TPB 256

// Clang ext_vector: a REAL vector type, accepted by __builtin_nontemporal_load
// (HIP's int4 is a HIP_vector_type class and is rejected by the builtin).
typedef int v4i __attribute__((ext_vector_type(4)));

__device__ __forceinline__ float bf16lo(unsigned u) {
    u <<= 16; return __builtin_bit_cast(float, u);
}
__device__ __forceinline__ float bf16hi(unsigned u) {
    u &= 0xffff0000u; return __builtin_bit_cast(float, u);
}
__device__ __forceinline__ unsigned bf16_rne(float f) {
    unsigned u = __builtin_bit_cast(unsigned, f);
    u += 0x7fffu + ((u >> 16) & 1u);     // RNE (finite inputs only)
    return u >> 16;
}
__device__ __forceinline__ unsigned pack_bf16(float a, float b) {
    return bf16_rne(a) | (bf16_rne(b) << 16);
}

// Counting grid barrier (monotonic target). G16-safe across incoherent XCD
// L2s: release __threadfence (writeback) before arrival; acquire-scope spin
// + __threadfence (invalidate) on exit. Deadlock-free because capacity
// (min(6 blk/CU LDS, 4 blk/CU launch_bounds) * 256 CU >= GRID) guarantees
// full co-residency.
__device__ __forceinline__ void grid_sync(unsigned* bar, unsigned target) {
    __syncthreads();
    if (threadIdx.x == 0) {
        __threadfence();                 // release: write back dirty lines
        atomicAdd(bar, 1u);
        while (__hip_atomic_load(bar, __ATOMIC_ACQUIRE,
                                 __HIP_MEMORY_SCOPE_AGENT) < target)
            __builtin_amdgcn_s_sleep(8);
        __threadfence();                 // acquire: invalidate stale lines
    }
    __syncthreads();
}

// ---------------------------------------------------------------------------
// ONE persistent kernel, 4 phases (round-12 fusion: ledger showed ~85 us of
// fixed per-iteration dispatch overhead vs ~70 us of modeled GPU work; fusing
// eliminates 3 inter-dispatch gaps AND makes the true GPU time visible as a
// single top-5 dispatch).
// ---------------------------------------------------------------------------
__global__ __launch_bounds__(TPB, 4) void fused_kernel(
        const float* __restrict__ x, const int* __restrict__ row,
        const int* __restrict__ col, const float* __restrict__ W,
        const float* __restrict__ b, int* __restrict__ cnt,
        unsigned* __restrict__ h2b, int* __restrict__ csr,
        unsigned* __restrict__ bar, float* __restrict__ out,
        int N, int E) {
    __shared__ float Ws[D * D];      // 16 KB
    __shared__ float xs[32][68];     // 8.7 KB (padded rows)

    const int tid = threadIdx.x;

    // ---- phase 0: cnt = 0 (stride covers N in one pass at this grid) ----
    for (int i = blockIdx.x * TPB + tid; i < N; i += GRID * TPB) cnt[i] = 0;
    grid_sync(bar, GRID * 1u);

    // ---- phase 1: XCD-sliced CSR fill (round-6 measured-best structure).
    // GRID % 8 == 0 -> vw&7 == blockIdx&7: each block keeps ONE slice, same
    // L2 affinity as the 6256-block version. ----
    {
        const int per = (N + NXCD - 1) / NXCD;
        const int nch = (E + TPB * EPT - 1) / (TPB * EPT);
        for (int vw = blockIdx.x; vw < nch * NXCD; vw += GRID) {
            const int slice = vw & (NXCD - 1);
            const int chunk = vw >> 3;
            const int lo = slice * per;
            const int hi = min(N, lo + per);
            const int e0 = (chunk * TPB + tid) * EPT;
            if (e0 + EPT <= E) {
                v4i c4 = __builtin_nontemporal_load((const v4i*)(col + e0));
                #pragma unroll
                for (int i = 0; i < EPT; ++i) {
                    int c = c4[i];
                    if (c >= lo && c < hi) {
                        int r = __builtin_nontemporal_load(row + e0 + i);
                        int pos = atomicAdd(&cnt[c], 1);
                        if (pos < CAP) csr[c * CAP + pos] = r;
                    }
                }
            } else {
                for (int i = 0; i < EPT; ++i) {
                    int e = e0 + i;
                    if (e < E) {
                        int c = col[e];
                        if (c >= lo && c < hi) {
                            int pos = atomicAdd(&cnt[c], 1);
                            if (pos < CAP) csr[c * CAP + pos] = row[e];
                        }
                    }
                }
            }
        }
    }
    grid_sync(bar, GRID * 2u);

    // ---- phase 2: h2b[n][d] = bf16(rsqrt(cnt+1) * (x@W)[d]) ----
    for (int i = tid; i < D * D; i += TPB) Ws[i] = W[i];
    {
        const int l16 = tid & 15;
        const int m   = tid >> 4;
        const float4* x4 = (const float4*)x;
        const int ntiles = (N + 63) / 64;
        for (int tile = blockIdx.x; tile < ntiles; tile += GRID) {
            const int base = tile * 64;
            for (int pass = 0; pass < 2; ++pass) {
                int nb = base + pass * 32;
                __syncthreads();         // Ws ready (first entry) / xs reuse
                for (int i = tid; i < 512; i += TPB) {
                    int r = i >> 4, seg = i & 15;
                    int n = nb + r;
                    float4 v = make_float4(0.f, 0.f, 0.f, 0.f);
                    if (n < N) v = x4[n * 16 + seg];
                    *(float4*)&xs[r][seg * 4] = v;
                }
                __syncthreads();

                float4 acc0 = make_float4(0.f, 0.f, 0.f, 0.f);
                float4 acc1 = make_float4(0.f, 0.f, 0.f, 0.f);
                #pragma unroll 4
                for (int k4 = 0; k4 < 16; ++k4) {
                    float4 xv0 = *(const float4*)&xs[m][k4 * 4];
                    float4 xv1 = *(const float4*)&xs[m + 16][k4 * 4];
                    #pragma unroll
                    for (int kk = 0; kk < 4; ++kk) {
                        float4 w4 = *(const float4*)&Ws[(k4 * 4 + kk) * D + l16 * 4];
                        float a0 = kk == 0 ? xv0.x : kk == 1 ? xv0.y : kk == 2 ? xv0.z : xv0.w;
                        float a1 = kk == 0 ? xv1.x : kk == 1 ? xv1.y : kk == 2 ? xv1.z : xv1.w;
                        acc0.x = fmaf(a0, w4.x, acc0.x); acc0.y = fmaf(a0, w4.y, acc0.y);
                        acc0.z = fmaf(a0, w4.z, acc0.z); acc0.w = fmaf(a0, w4.w, acc0.w);
                        acc1.x = fmaf(a1, w4.x, acc1.x); acc1.y = fmaf(a1, w4.y, acc1.y);
                        acc1.w = fmaf(a1, w4.w, acc1.w); acc1.z = fmaf(a1, w4.z, acc1.z);
                    }
                }

                int n0 = nb + m, n1 = nb + m + 16;
                if (n0 < N) {
                    float dn = rsqrtf((float)(cnt[n0] + 1));
                    uint2 p; p.x = pack_bf16(acc0.x * dn, acc0.y * dn);
                    p.y = pack_bf16(acc0.z * dn, acc0.w * dn);
                    ((uint2*)h2b)[n0 * 16 + l16] = p;
                }
                if (n1 < N) {
                    float dn = rsqrtf((float)(cnt[n1] + 1));
                    uint2 p; p.x = pack_bf16(acc1.x * dn, acc1.y * dn);
                    p.y = pack_bf16(acc1.z * dn, acc1.w * dn);
                    ((uint2*)h2b)[n1 * 16 + l16] = p;
                }
            }
        }
    }
    grid_sync(bar, GRID * 3u);

    // ---- phase 3: group-per-node gather-reduce (round-11 structure) ----
    {
        const int l16 = tid & 15;
        const int gid = tid >> 4;            // group in block (0..15)
        const int gw  = gid & 3;             // group in wave (0..3)
        const uint2* hb = (const uint2*)h2b;
        const int ntiles = (N + 15) / 16;
        for (int tile = blockIdx.x; tile < ntiles; tile += GRID) {
            const int c = tile * 16 + gid;
            if (c < N) {
                const float4 bv = ((const float4*)b)[l16];
                const float4 xv = ((const float4*)x)[c * 16 + l16];

                uint2 v = hb[c * 16 + l16];  // self-loop (pre-scaled)
                float4 acc;
                acc.x = bf16lo(v.x); acc.y = bf16hi(v.x);
                acc.z = bf16lo(v.y); acc.w = bf16hi(v.y);

                int n = cnt[c]; n = n < CAP ? n : CAP;
                const int* cb = csr + c * CAP;

                for (int j0 = 0; j0 < n; j0 += 16) {
                    int idx = (j0 + l16 < n) ? cb[j0 + l16] : 0;
                    int m = n - j0; m = m < 16 ? m : 16;
                    #pragma unroll 4
                    for (int jj = 0; jj < m; ++jj) {
                        int r = __shfl(idx, gw * 16 + jj);   // own group only
                        uint2 w = hb[r * 16 + l16];
                        acc.x += bf16lo(w.x); acc.y += bf16hi(w.x);
                        acc.z += bf16lo(w.y); acc.w += bf16hi(w.y);
                    }
                }

                float dc = rsqrtf((float)(cnt[c] + 1));
                float4 o;
                o.x = fmaf(dc, acc.x, bv.x); o.x = o.x > 0.0f ? o.x : 0.0f; o.x += xv.x;
                o.y = fmaf(dc, acc.y, bv.y); o.y = o.y > 0.0f ? o.y : 0.0f; o.y += xv.y;
                o.z = fmaf(dc, acc.z, bv.z); o.z = o.z > 0.0f ? o.z : 0.0f; o.z += xv.z;
                o.w = fmaf(dc, acc.w, bv.w); o.w = o.w > 0.0f ? o.w : 0.0f; o.w += xv.w;
                ((float4*)out)[c * 16 + l16] = o;
            }
        }
    }
}

extern "C" void kernel_launch(void* const* d_in, const int* in_sizes, int n_in,
                              void* d_out, int out_size, void* d_ws, size_t ws_size,
                              hipStream_t stream) {
    const float* x   = (const float*)d_in[0];
    const int*   ei  = (const int*)d_in[1];   // [2, E] flat: [0..E)=row(src), [E..2E)=col(dst)
    const float* W   = (const float*)d_in[2];
    const float* b   = (const float*)d_in[3];
    float*       out = (float*)d_out;

    const int N = in_sizes[0] / D;            // 50000
    const int E = in_sizes[1] / 2;            // 800000
    const int* row = ei;
    const int* col = ei + E;

    // workspace layout (4-byte elements): cnt[N] | h2b[N*D/2] | csr[N*CAP] | bar
    int*      cnt = (int*)d_ws;
    unsigned* h2b = (unsigned*)(cnt + N);
    int*      csr = (int*)(h2b + (size_t)N * D / 2);
    unsigned* bar = (unsigned*)(csr + (size_t)N * CAP);

    hipMemsetAsync(bar, 0, sizeof(unsigned), stream);   // ws is re-poisoned per iter
    fused_kernel<<<GRID, TPB, 0, stream>>>(x, row, col, W, b, cnt, h2b, csr,
                                           bar, out, N, E);
}

// Round 18
// 159.332 us; speedup vs baseline: 3.5379x; 3.5379x over previous
//
#include <hip/hip_runtime.h>
#include <hip/hip_bf16.h>

#define D 64
#define CAP 64    // fixed CSR row capacity; deg ~ Poisson(16), P(deg>=64) ~ 1e-20
#define NSLICE 4  // round-14: 4 destination slices (was 8) -> col scanned 4x not 8x
#define EPT 8     // round-14: 8 edges/thread (two dwordx4 col loads) -> 2x ILP
#define TPB 256

// Clang ext_vector: a REAL vector type, accepted by __builtin_nontemporal_load
// (HIP's int4 is a HIP_vector_type class and is rejected by the builtin).
typedef int v4i __attribute__((ext_vector_type(4)));

__device__ __forceinline__ float bf16lo(unsigned u) {
    u <<= 16; return __builtin_bit_cast(float, u);
}
__device__ __forceinline__ float bf16hi(unsigned u) {
    u &= 0xffff0000u; return __builtin_bit_cast(float, u);
}
// round-to-nearest-even bf16 truncation of a float, returned as top-16 bits
__device__ __forceinline__ unsigned bf16_rne(float f) {
    unsigned u = __builtin_bit_cast(unsigned, f);
    u += 0x7fffu + ((u >> 16) & 1u);     // RNE (finite inputs only)
    return u >> 16;
}
__device__ __forceinline__ unsigned pack_bf16(float a, float b) {
    return bf16_rne(a) | (bf16_rne(b) << 16);
}

// ---------------------------------------------------------------------------
// Kernel 1: cnt[i] = 0
// ---------------------------------------------------------------------------
__global__ void zero_cnt_kernel(int* __restrict__ cnt, int N) {
    int i = blockIdx.x * blockDim.x + threadIdx.x;
    if (i < N) cnt[i] = 0;
}

// ---------------------------------------------------------------------------
// Kernel 2: sliced single-pass fixed-capacity CSR build.
// History: r6 (8-slice, EPT=4): 45.4 us, WRITE 30 MB, FETCH 33 MB.
//          r7 (XCC_ID work-queues): 277 us -> reverted; r13 (persistent
//          fusion, 1024 blk): phase starved of TLP -> reverted. Fill is
//          LATENCY-bound (VALU 3.5%), so r14 trades slice residency for
//          issue count: 4 slices halve the col re-scan; EPT=8 doubles
//          per-thread in-flight edges. 1564 blocks still >= full residency.
// ---------------------------------------------------------------------------
__global__ __launch_bounds__(TPB) void fill_csr_sliced_kernel(
        const int* __restrict__ row, const int* __restrict__ col,
        int* __restrict__ cnt, int* __restrict__ csr, int E, int N) {
    const int slice = blockIdx.x & (NSLICE - 1);
    const int chunk = blockIdx.x >> 2;           // log2(NSLICE)
    const int per = (N + NSLICE - 1) / NSLICE;
    const int lo = slice * per;
    const int hi = min(N, lo + per);

    const int e0 = (chunk * TPB + (int)threadIdx.x) * EPT;
    if (e0 + EPT <= E) {
        v4i c4a = __builtin_nontemporal_load((const v4i*)(col + e0));
        v4i c4b = __builtin_nontemporal_load((const v4i*)(col + e0 + 4));
        #pragma unroll
        for (int i = 0; i < EPT; ++i) {
            int c = (i < 4) ? c4a[i] : c4b[i - 4];
            if (c >= lo && c < hi) {
                int r = __builtin_nontemporal_load(row + e0 + i);
                int pos = atomicAdd(&cnt[c], 1);
                if (pos < CAP) csr[c * CAP + pos] = r;
            }
        }
    } else {
        for (int i = 0; i < EPT; ++i) {
            int e = e0 + i;
            if (e < E) {
                int c = col[e];
                if (c >= lo && c < hi) {
                    int pos = atomicAdd(&cnt[c], 1);
                    if (pos < CAP) csr[c * CAP + pos] = row[e];
                }
            }
        }
    }
}

// ---------------------------------------------------------------------------
// Kernel 3: h2b[n][d] = bf16( rsqrt(cnt[n]+1) * (x[n] @ W)[d] )
// Block = 64 nodes (2 passes of 32). W fp32 in LDS (16 KB). Thread owns
// 2 nodes x 4 dims -> 8 acc regs (no spills). W reads are ds_read_b128
// broadcasts across node-groups; x rows staged in padded LDS.
// ---------------------------------------------------------------------------
__global__ __launch_bounds__(256) void transform_kernel(
        const float* __restrict__ x, const float* __restrict__ W,
        const int* __restrict__ cnt, unsigned* __restrict__ h2b, int N) {
    __shared__ float Ws[D * D];      // W[k][d], 16 KB
    __shared__ float xs[32][68];     // 32 rows, padded to 68 floats (bank spread)

    for (int i = threadIdx.x; i < D * D; i += 256) Ws[i] = W[i];

    const int l16 = threadIdx.x & 15;    // dim group: d = l16*4 .. l16*4+3
    const int m   = threadIdx.x >> 4;    // node sub-index 0..15
    const int base = blockIdx.x * 64;
    const float4* x4 = (const float4*)x;

    for (int pass = 0; pass < 2; ++pass) {
        int nb = base + pass * 32;
        __syncthreads();                 // Ws ready (pass 0) / xs reuse (pass 1)
        for (int i = threadIdx.x; i < 512; i += 256) {
            int r = i >> 4, seg = i & 15;
            int n = nb + r;
            float4 v = make_float4(0.f, 0.f, 0.f, 0.f);
            if (n < N) v = x4[n * 16 + seg];
            *(float4*)&xs[r][seg * 4] = v;
        }
        __syncthreads();

        float4 acc0 = make_float4(0.f, 0.f, 0.f, 0.f);
        float4 acc1 = make_float4(0.f, 0.f, 0.f, 0.f);
        #pragma unroll 4
        for (int k4 = 0; k4 < 16; ++k4) {
            float4 xv0 = *(const float4*)&xs[m][k4 * 4];
            float4 xv1 = *(const float4*)&xs[m + 16][k4 * 4];
            #pragma unroll
            for (int kk = 0; kk < 4; ++kk) {
                float4 w4 = *(const float4*)&Ws[(k4 * 4 + kk) * D + l16 * 4];
                float a0 = kk == 0 ? xv0.x : kk == 1 ? xv0.y : kk == 2 ? xv0.z : xv0.w;
                float a1 = kk == 0 ? xv1.x : kk == 1 ? xv1.y : kk == 2 ? xv1.z : xv1.w;
                acc0.x = fmaf(a0, w4.x, acc0.x); acc0.y = fmaf(a0, w4.y, acc0.y);
                acc0.z = fmaf(a0, w4.z, acc0.z); acc0.w = fmaf(a0, w4.w, acc0.w);
                acc1.x = fmaf(a1, w4.x, acc1.x); acc1.y = fmaf(a1, w4.y, acc1.y);
                acc1.z = fmaf(a1, w4.z, acc1.z); acc1.w = fmaf(a1, w4.w, acc1.w);
            }
        }

        int n0 = nb + m, n1 = nb + m + 16;
        if (n0 < N) {
            float dn = rsqrtf((float)(cnt[n0] + 1));
            uint2 p; p.x = pack_bf16(acc0.x * dn, acc0.y * dn);
            p.y = pack_bf16(acc0.z * dn, acc0.w * dn);
            ((uint2*)h2b)[n0 * 16 + l16] = p;
        }
        if (n1 < N) {
            float dn = rsqrtf((float)(cnt[n1] + 1));
            uint2 p; p.x = pack_bf16(acc1.x * dn, acc1.y * dn);
            p.y = pack_bf16(acc1.z * dn, acc1.w * dn);
            ((uint2*)h2b)[n1 * 16 + l16] = p;
        }
    }
}

// ---------------------------------------------------------------------------
// Kernel 4: group-per-node gather-reduce (round-11 measured structure).
// Each 16-lane group owns ONE node and ALL 64 dims; no cross-lane reduction;
// 4 independent head chains per wave; __shfl sources confined to own group
// (all 16 lanes share c and n -> round-8 EXEC hazard excluded).
// Fused epilogue: out = relu(dinv[c]*acc + b) + x.
// ---------------------------------------------------------------------------
__global__ __launch_bounds__(256) void agg_kernel(
        const float* __restrict__ x, const float* __restrict__ b,
        const unsigned* __restrict__ h2b, const int* __restrict__ cnt,
        const int* __restrict__ csr, float* __restrict__ out, int N) {
    const int l16 = threadIdx.x & 15;
    const int gid = threadIdx.x >> 4;          // group in block (0..15)
    const int gw  = gid & 3;                   // group in wave (0..3)
    const int c = blockIdx.x * 16 + gid;
    if (c >= N) return;

    const uint2* hb = (const uint2*)h2b;

    // Early independent loads (epilogue data) to overlap with gather chain.
    const float4 bv = ((const float4*)b)[l16];
    const float4 xv = ((const float4*)x)[c * 16 + l16];

    // self-loop term (h2 pre-scaled); every lane owns its own 4 dims
    uint2 v = hb[c * 16 + l16];
    float4 acc;
    acc.x = bf16lo(v.x); acc.y = bf16hi(v.x);
    acc.z = bf16lo(v.y); acc.w = bf16hi(v.y);

    int n = cnt[c]; n = n < CAP ? n : CAP;
    const int* cb = csr + c * CAP;

    for (int j0 = 0; j0 < n; j0 += 16) {
        int idx = (j0 + l16 < n) ? cb[j0 + l16] : 0;   // 64 B group load
        int m = n - j0; m = m < 16 ? m : 16;
        #pragma unroll 4
        for (int jj = 0; jj < m; ++jj) {
            int r = __shfl(idx, gw * 16 + jj);         // source in own group
            uint2 w = hb[r * 16 + l16];                // 128 B group gather
            acc.x += bf16lo(w.x); acc.y += bf16hi(w.x);
            acc.z += bf16lo(w.y); acc.w += bf16hi(w.y);
        }
    }

    float dc = rsqrtf((float)(cnt[c] + 1));
    float4 o;
    o.x = fmaf(dc, acc.x, bv.x); o.x = o.x > 0.0f ? o.x : 0.0f; o.x += xv.x;
    o.y = fmaf(dc, acc.y, bv.y); o.y = o.y > 0.0f ? o.y : 0.0f; o.y += xv.y;
    o.z = fmaf(dc, acc.z, bv.z); o.z = o.z > 0.0f ? o.z : 0.0f; o.z += xv.z;
    o.w = fmaf(dc, acc.w, bv.w); o.w = o.w > 0.0f ? o.w : 0.0f; o.w += xv.w;
    ((float4*)out)[c * 16 + l16] = o;
}

extern "C" void kernel_launch(void* const* d_in, const int* in_sizes, int n_in,
                              void* d_out, int out_size, void* d_ws, size_t ws_size,
                              hipStream_t stream) {
    const float* x   = (const float*)d_in[0];
    const int*   ei  = (const int*)d_in[1];   // [2, E] flat: [0..E)=row(src), [E..2E)=col(dst)
    const float* W   = (const float*)d_in[2];
    const float* b   = (const float*)d_in[3];
    float*       out = (float*)d_out;

    const int N = in_sizes[0] / D;            // 50000
    const int E = in_sizes[1] / 2;            // 800000
    const int* row = ei;
    const int* col = ei + E;

    // workspace layout (4-byte elements): cnt[N] | h2b[N*D/2 uints] | csr[N*CAP]
    int*      cnt = (int*)d_ws;
    unsigned* h2b = (unsigned*)(cnt + N);
    int*      csr = (int*)(h2b + (size_t)N * D / 2);

    zero_cnt_kernel<<<(N + 255) / 256, 256, 0, stream>>>(cnt, N);

    const int fill_chunks = (E + TPB * EPT - 1) / (TPB * EPT);   // 391
    fill_csr_sliced_kernel<<<fill_chunks * NSLICE, TPB, 0, stream>>>(row, col, cnt, csr, E, N);

    transform_kernel<<<(N + 63) / 64, 256, 0, stream>>>(x, W, cnt, h2b, N);
    agg_kernel<<<(N + 15) / 16, 256, 0, stream>>>(x, b, h2b, cnt, csr, out, N);
}